// Round 15
// baseline (586.667 us; speedup 1.0000x reference)
//
#include <hip/hip_runtime.h>
#include <hip/hip_bf16.h>
#include <cstdint>
#include <cstddef>

// Qwen3 MoE layer: T=2048 tokens, H=1024 hidden, E=64 experts, I=768, top-K=8
#define T_TOK 2048
#define H_DIM 1024
#define E_NUM 64
#define I_DIM 768
#define K_TOP 8

typedef __attribute__((ext_vector_type(8))) __bf16 bf16x8;
typedef __attribute__((ext_vector_type(8))) unsigned short u16x8;
typedef __attribute__((ext_vector_type(4))) float f32x4;
typedef unsigned short ushort_t;

__device__ __forceinline__ unsigned short f2bf(float f) {
  uint32_t u = __builtin_bit_cast(uint32_t, f);
  u += 0x7fffu + ((u >> 16) & 1u);
  return (unsigned short)(u >> 16);
}

__device__ __forceinline__ u16x8 cvt8b(f32x4 a, f32x4 b) {
  bf16x8 r;
  r[0] = (__bf16)a[0]; r[1] = (__bf16)a[1]; r[2] = (__bf16)a[2]; r[3] = (__bf16)a[3];
  r[4] = (__bf16)b[0]; r[5] = (__bf16)b[1]; r[6] = (__bf16)b[2]; r[7] = (__bf16)b[3];
  return __builtin_bit_cast(u16x8, r);
}

// async 16B global -> LDS; dest = wave-uniform base (HW adds lane*16)
__device__ __forceinline__ void async16(const void* l, const void* g) {
  __builtin_amdgcn_global_load_lds(
      (const __attribute__((address_space(1))) unsigned int*)g,
      (__attribute__((address_space(3))) unsigned int*)l, 16, 0, 0);
}

// Bijective XCD-contiguous decode over the ACTIVE index space [0, n_act)
__device__ __forceinline__ int xcd_decode(int wg0, int n_act) {
  int q = n_act >> 3, r = n_act & 7;
  int xcd = wg0 & 7, rank = wg0 >> 3;
  int cnt = q + (xcd < r ? 1 : 0);
  if (rank >= cnt) return -1;
  return (xcd < r ? xcd * (q + 1) : r * (q + 1) + (xcd - r) * q) + rank;
}

// ---------------- x f32 -> bf16 pre-cast ----------------
__global__ __launch_bounds__(256) void xcast_kernel(const float* __restrict__ x,
                                                    ushort_t* __restrict__ xb) {
  int i = blockIdx.x * 256 + threadIdx.x;
  const f32x4* s = (const f32x4*)(x + (size_t)i * 8);
  *(u16x8*)(xb + (size_t)i * 8) = cvt8b(s[0], s[1]);
}

// ---------------- router: 4 tokens/block ----------------
__global__ __launch_bounds__(64) void router_kernel(
    const float* __restrict__ x, const float* __restrict__ wr,
    int* __restrict__ topk_id, float* __restrict__ topk_w,
    int* __restrict__ counts) {
  const int t0 = blockIdx.x * 4;
  const int e = threadIdx.x;
  const float4* wv = (const float4*)(wr + (size_t)e * H_DIM);
  const float4* xv0 = (const float4*)(x + (size_t)t0 * H_DIM);
  const float4* xv1 = (const float4*)(x + (size_t)(t0 + 1) * H_DIM);
  const float4* xv2 = (const float4*)(x + (size_t)(t0 + 2) * H_DIM);
  const float4* xv3 = (const float4*)(x + (size_t)(t0 + 3) * H_DIM);
  float acc0 = 0.f, acc1 = 0.f, acc2 = 0.f, acc3 = 0.f;
#pragma unroll 4
  for (int i = 0; i < H_DIM / 4; ++i) {
    float4 b = wv[i];
    float4 a0 = xv0[i], a1 = xv1[i], a2 = xv2[i], a3 = xv3[i];
    acc0 = fmaf(a0.x, b.x, fmaf(a0.y, b.y, fmaf(a0.z, b.z, fmaf(a0.w, b.w, acc0))));
    acc1 = fmaf(a1.x, b.x, fmaf(a1.y, b.y, fmaf(a1.z, b.z, fmaf(a1.w, b.w, acc1))));
    acc2 = fmaf(a2.x, b.x, fmaf(a2.y, b.y, fmaf(a2.z, b.z, fmaf(a2.w, b.w, acc2))));
    acc3 = fmaf(a3.x, b.x, fmaf(a3.y, b.y, fmaf(a3.z, b.z, fmaf(a3.w, b.w, acc3))));
  }
  float accs[4] = {acc0, acc1, acc2, acc3};
#pragma unroll 1
  for (int tt = 0; tt < 4; ++tt) {
    int t = t0 + tt;
    float acc = accs[tt];
    float m = acc;
    for (int o = 32; o; o >>= 1) m = fmaxf(m, __shfl_xor(m, o));
    float p = __expf(acc - m);
    float s = p;
    for (int o = 32; o; o >>= 1) s += __shfl_xor(s, o);
    p /= s;
    float v = p;
    int sid = 0;
    float sw = 0.f;
    for (int k = 0; k < K_TOP; ++k) {
      float bv = v;
      int bi = e;
      for (int o = 32; o; o >>= 1) {
        float ov = __shfl_xor(bv, o);
        int oi = __shfl_xor(bi, o);
        if (ov > bv || (ov == bv && oi < bi)) { bv = ov; bi = oi; }
      }
      if (e == k) { sid = bi; sw = bv; }
      if (e == bi) v = -1.f;
    }
    float ssum = (e < K_TOP) ? sw : 0.f;
    for (int o = 32; o; o >>= 1) ssum += __shfl_xor(ssum, o);
    if (e < K_TOP) {
      topk_id[t * K_TOP + e] = sid;
      topk_w[t * K_TOP + e] = sw / ssum;
      atomicAdd(&counts[sid], 1);
    }
  }
}

// ---------------- scan: offsets + tile list (BM=256, max 2 tiles/expert) ----------------
__global__ __launch_bounds__(64) void scan_kernel(
    const int* __restrict__ counts, int* __restrict__ offsets,
    int* __restrict__ cursor, int* __restrict__ tile_list,
    int* __restrict__ n_tiles) {
  int e = threadIdx.x;
  int ne = counts[e];
  int x = ne;
  for (int o = 1; o < 64; o <<= 1) {
    int v = __shfl_up(x, o);
    if (e >= o) x += v;
  }
  int excl = x - ne;
  offsets[e] = excl;
  cursor[e] = excl;
  int ntl = (ne + 255) >> 8;
  if (ntl > 2) ntl = 2;
  int y2 = ntl;
  for (int o = 1; o < 64; o <<= 1) {
    int v = __shfl_up(y2, o);
    if (e >= o) y2 += v;
  }
  int texcl = y2 - ntl;
  for (int m = 0; m < ntl; ++m) tile_list[texcl + m] = (e << 2) | m;
  if (e == 63) *n_tiles = texcl + ntl;
}

__global__ __launch_bounds__(256) void build_kernel(
    const int* __restrict__ topk_id, const float* __restrict__ topk_w,
    int* __restrict__ cursor, int* __restrict__ pair_token, float* __restrict__ pair_w) {
  int i = blockIdx.x * 256 + threadIdx.x;
  int t = i >> 3;
  int e = topk_id[i];
  int pos = atomicAdd(&cursor[e], 1);
  pair_token[pos] = t;
  pair_w[pos] = topk_w[i];
}

// bf16 LDS rows: 32 bf16 = 4 chunks of 16B; chunk slot = c ^ ((row>>1)&3)

// ================= stage 1: h = silu(X Wg^T) * (X Wu^T) =================
// Block 256(M tokens) x 256(N = 128 G-rows || 128 U-rows of one I-block), BK=32.
// 8 waves 2M x 4N, wave tile 128x64, acc = 128 VGPR (halves LDS bytes/FLOP).
// launch_bounds(512,2): VGPR budget 256 -> no spill (R14's bug was the 128 cap).
#define GU_NIT 32

__global__ __launch_bounds__(512, 2) void gemm_gu_kernel(
    const ushort_t* __restrict__ xb, const float* __restrict__ wg,
    const float* __restrict__ wu, const int* __restrict__ offsets,
    const int* __restrict__ counts, const int* __restrict__ pair_token,
    const int* __restrict__ tile_list, const int* __restrict__ n_tiles,
    ushort_t* __restrict__ h_buf) {
  int idx = xcd_decode(blockIdx.x, (*n_tiles) * 6);
  if (idx < 0) return;
  int tl = idx / 6, nt = idx - tl * 6;
  int ent = tile_list[tl];
  int e = ent >> 2, mt = ent & 3;
  int ne = counts[e], off = offsets[e];
  int ib = nt * 128;
  int vr = ne - mt * 256;
  if (vr <= 0) return;
  if (vr > 256) vr = 256;

  // arena: X 2x16KB @0, B 2x16KB @32K, sTok @64K; epilogue reuses [0,64K) as f32 ex
  __shared__ __align__(16) char L[66560];
  ushort_t* Xs = (ushort_t*)L;
  ushort_t* Bl = (ushort_t*)(L + 32768);
  int* sTok = (int*)(L + 65536);

  const int tid = threadIdx.x;
  const int lane = tid & 63;
  const int wid = tid >> 6;            // 0..7
  const int wrM = wid >> 2, wrN = wid & 3;  // 2M x 4N
  const int lrow = lane & 15, lk = lane >> 4;

  if (tid < 256) {
    int p = mt * 256 + tid;
    sTok[tid] = pair_token[off + (p < ne ? p : ne - 1)];
  }
  __syncthreads();

  // X DMA: 1024 chunks of 16B, 2/thread; linear dest + inverse-swizzled src
  const ushort_t* xsrc[2];
  int xdst[2];
#pragma unroll
  for (int j = 0; j < 2; ++j) {
    int p = j * 512 + tid;
    int row = p >> 2, c = p & 3;
    xsrc[j] = xb + (size_t)sTok[row] * H_DIM + ((c ^ ((row >> 1) & 3)) << 3);
    xdst[j] = (j * 512 + wid * 64) * 8;
  }
  // W staging: row brow = tid>>1 (0-127 G, 128-255 U), chunk pair (tid&1)
  const int brow = tid >> 1;
  const int cs0 = (tid & 1) * 2, cs1 = cs0 + 1;
  const float* bq = (brow < 128)
      ? wg + ((size_t)e * I_DIM + ib + brow) * H_DIM
      : wu + ((size_t)e * I_DIM + ib + brow - 128) * H_DIM;
  const float* bsrc0 = bq + cs0 * 8;
  const float* bsrc1 = bq + cs1 * 8;
  const int bd0 = (brow * 4 + (cs0 ^ ((brow >> 1) & 3))) * 8;
  const int bd1 = (brow * 4 + (cs1 ^ ((brow >> 1) & 3))) * 8;

  const bool wact = (wrM * 128) < vr;

  f32x4 acc[8][4];
#pragma unroll
  for (int mi = 0; mi < 8; ++mi)
#pragma unroll
    for (int ni = 0; ni < 4; ++ni) acc[mi][ni] = f32x4{0.f, 0.f, 0.f, 0.f};

#define GU_XDMA(B, K0)                                 \
  do {                                                 \
    async16(&Xs[(B) * 8192 + xdst[0]], xsrc[0] + (K0)); \
    async16(&Xs[(B) * 8192 + xdst[1]], xsrc[1] + (K0)); \
  } while (0)

  f32x4 w0, w1, w2, w3;
  // prologue: tile 0 into buf 0
  GU_XDMA(0, 0);
  w0 = *(const f32x4*)(bsrc0);
  w1 = *(const f32x4*)(bsrc0 + 4);
  w2 = *(const f32x4*)(bsrc1);
  w3 = *(const f32x4*)(bsrc1 + 4);
  *(u16x8*)&Bl[bd0] = cvt8b(w0, w1);
  *(u16x8*)&Bl[bd1] = cvt8b(w2, w3);
  asm volatile("s_waitcnt vmcnt(0) lgkmcnt(0)" ::: "memory");
  __builtin_amdgcn_s_barrier();

#pragma unroll 1
  for (int K = 0; K < GU_NIT; ++K) {
    const int B = K & 1;
    if (K + 1 < GU_NIT) {
      const int kn = (K + 1) * 32;
      GU_XDMA(B ^ 1, kn);
      w0 = *(const f32x4*)(bsrc0 + kn);
      w1 = *(const f32x4*)(bsrc0 + kn + 4);
      w2 = *(const f32x4*)(bsrc1 + kn);
      w3 = *(const f32x4*)(bsrc1 + kn + 4);
    }
    if (wact) {
      u16x8 bf[4];
#pragma unroll
      for (int ni = 0; ni < 4; ++ni) {
        int br = wrN * 64 + ni * 16 + lrow;
        bf[ni] = *(const u16x8*)&Bl[B * 8192 + br * 32 + ((lk ^ ((br >> 1) & 3)) << 3)];
      }
#pragma unroll
      for (int mi = 0; mi < 8; ++mi) {
        int r = wrM * 128 + mi * 16 + lrow;
        u16x8 af = *(const u16x8*)&Xs[B * 8192 + r * 32 + ((lk ^ ((r >> 1) & 3)) << 3)];
#pragma unroll
        for (int ni = 0; ni < 4; ++ni)
          acc[mi][ni] = __builtin_amdgcn_mfma_f32_16x16x32_bf16(
              __builtin_bit_cast(bf16x8, af), __builtin_bit_cast(bf16x8, bf[ni]),
              acc[mi][ni], 0, 0, 0);
      }
    }
    asm volatile("s_waitcnt vmcnt(0)" ::: "memory");
    if (K + 1 < GU_NIT) {
      *(u16x8*)&Bl[(B ^ 1) * 8192 + bd0] = cvt8b(w0, w1);
      *(u16x8*)&Bl[(B ^ 1) * 8192 + bd1] = cvt8b(w2, w3);
    }
    asm volatile("s_waitcnt lgkmcnt(0)" ::: "memory");
    __builtin_amdgcn_s_barrier();
  }
#undef GU_XDMA

  // epilogue: cross-wave SwiGLU via f32 LDS exchange, 2 rounds (q = 0,1)
  float* ex = (float*)L;  // [256 rows][64 cols] = 64 KB
#pragma unroll 1
  for (int q = 0; q < 2; ++q) {
    if (wrN == 2 + q) {  // U waves dump
#pragma unroll
      for (int mi = 0; mi < 8; ++mi)
#pragma unroll
        for (int ni = 0; ni < 4; ++ni)
#pragma unroll
          for (int r = 0; r < 4; ++r)
            ex[(wrM * 128 + mi * 16 + lk * 4 + r) * 64 + ni * 16 + lrow] = acc[mi][ni][r];
    }
    __syncthreads();
    if (wrN == q) {  // G waves consume + store h
#pragma unroll
      for (int mi = 0; mi < 8; ++mi)
#pragma unroll
        for (int ni = 0; ni < 4; ++ni)
#pragma unroll
          for (int r = 0; r < 4; ++r) {
            int grow = wrM * 128 + mi * 16 + lk * 4 + r;
            if (grow < vr) {
              float g = acc[mi][ni][r];
              float u = ex[grow * 64 + ni * 16 + lrow];
              float hv = g / (1.f + __expf(-g)) * u;
              int col = ib + q * 64 + ni * 16 + lrow;
              h_buf[(size_t)(off + mt * 256 + grow) * I_DIM + col] = f2bf(hv);
            }
          }
    }
    __syncthreads();
  }
}

// ================= stage 2: y += route_w * (h Wd^T) =================
// Block 256(M) x 256(N H-cols), BK=32, 8 waves 2M x 4N, wave 128x64, acc=128.
#define DN_NIT 24

__global__ __launch_bounds__(512, 2) void gemm_down_kernel(
    const ushort_t* __restrict__ h_buf, const float* __restrict__ wd,
    const int* __restrict__ offsets, const int* __restrict__ counts,
    const int* __restrict__ pair_token, const float* __restrict__ pair_w,
    const int* __restrict__ tile_list, const int* __restrict__ n_tiles,
    float* __restrict__ y) {
  int idx = xcd_decode(blockIdx.x, (*n_tiles) * 4);
  if (idx < 0) return;
  int tl = idx >> 2, nt = idx & 3;
  int ent = tile_list[tl];
  int e = ent >> 2, mt = ent & 3;
  int ne = counts[e], off = offsets[e];
  int hb = nt * 256;
  int vr = ne - mt * 256;
  if (vr <= 0) return;
  if (vr > 256) vr = 256;

  __shared__ __align__(16) char L[67584];  // A 2x16K @0, B 2x16K @32K, tok/pw @64K
  ushort_t* Ah = (ushort_t*)L;
  ushort_t* Bl = (ushort_t*)(L + 32768);
  int* sTok = (int*)(L + 65536);
  float* sPw = (float*)(L + 66560);

  const int tid = threadIdx.x;
  const int lane = tid & 63;
  const int wid = tid >> 6;
  const int wrM = wid >> 2, wrN = wid & 3;
  const int lrow = lane & 15, lk = lane >> 4;

  if (tid < 256) {
    int p = mt * 256 + tid;
    int ix = off + (p < ne ? p : ne - 1);
    sTok[tid] = pair_token[ix];
    sPw[tid] = pair_w[ix];
  }
  __syncthreads();

  const ushort_t* asrc[2];
  int adst[2];
#pragma unroll
  for (int j = 0; j < 2; ++j) {
    int p = j * 512 + tid;
    int row = p >> 2, c = p & 3;
    int pr = mt * 256 + row;
    int hr = off + (pr < ne ? pr : ne - 1);
    asrc[j] = h_buf + (size_t)hr * I_DIM + ((c ^ ((row >> 1) & 3)) << 3);
    adst[j] = (j * 512 + wid * 64) * 8;
  }
  // Wd staging: row brow = tid>>1 (H-col hb+brow), chunk pair (tid&1)
  const int brow = tid >> 1;
  const int cs0 = (tid & 1) * 2, cs1 = cs0 + 1;
  const float* bq = wd + ((size_t)e * H_DIM + hb + brow) * I_DIM;
  const float* bsrc0 = bq + cs0 * 8;
  const float* bsrc1 = bq + cs1 * 8;
  const int bd0 = (brow * 4 + (cs0 ^ ((brow >> 1) & 3))) * 8;
  const int bd1 = (brow * 4 + (cs1 ^ ((brow >> 1) & 3))) * 8;

  const bool wact = (wrM * 128) < vr;

  f32x4 acc[8][4];
#pragma unroll
  for (int mi = 0; mi < 8; ++mi)
#pragma unroll
    for (int ni = 0; ni < 4; ++ni) acc[mi][ni] = f32x4{0.f, 0.f, 0.f, 0.f};

#define DN_ADMA(B, K0)                                  \
  do {                                                  \
    async16(&Ah[(B) * 8192 + adst[0]], asrc[0] + (K0)); \
    async16(&Ah[(B) * 8192 + adst[1]], asrc[1] + (K0)); \
  } while (0)

  f32x4 w0, w1, w2, w3;
  DN_ADMA(0, 0);
  w0 = *(const f32x4*)(bsrc0);
  w1 = *(const f32x4*)(bsrc0 + 4);
  w2 = *(const f32x4*)(bsrc1);
  w3 = *(const f32x4*)(bsrc1 + 4);
  *(u16x8*)&Bl[bd0] = cvt8b(w0, w1);
  *(u16x8*)&Bl[bd1] = cvt8b(w2, w3);
  asm volatile("s_waitcnt vmcnt(0) lgkmcnt(0)" ::: "memory");
  __builtin_amdgcn_s_barrier();

#pragma unroll 1
  for (int K = 0; K < DN_NIT; ++K) {
    const int B = K & 1;
    if (K + 1 < DN_NIT) {
      const int kn = (K + 1) * 32;
      DN_ADMA(B ^ 1, kn);
      w0 = *(const f32x4*)(bsrc0 + kn);
      w1 = *(const f32x4*)(bsrc0 + kn + 4);
      w2 = *(const f32x4*)(bsrc1 + kn);
      w3 = *(const f32x4*)(bsrc1 + kn + 4);
    }
    if (wact) {
      u16x8 bf[4];
#pragma unroll
      for (int ni = 0; ni < 4; ++ni) {
        int br = wrN * 64 + ni * 16 + lrow;
        bf[ni] = *(const u16x8*)&Bl[B * 8192 + br * 32 + ((lk ^ ((br >> 1) & 3)) << 3)];
      }
#pragma unroll
      for (int mi = 0; mi < 8; ++mi) {
        int r = wrM * 128 + mi * 16 + lrow;
        u16x8 af = *(const u16x8*)&Ah[B * 8192 + r * 32 + ((lk ^ ((r >> 1) & 3)) << 3)];
#pragma unroll
        for (int ni = 0; ni < 4; ++ni)
          acc[mi][ni] = __builtin_amdgcn_mfma_f32_16x16x32_bf16(
              __builtin_bit_cast(bf16x8, af), __builtin_bit_cast(bf16x8, bf[ni]),
              acc[mi][ni], 0, 0, 0);
      }
    }
    asm volatile("s_waitcnt vmcnt(0)" ::: "memory");
    if (K + 1 < DN_NIT) {
      *(u16x8*)&Bl[(B ^ 1) * 8192 + bd0] = cvt8b(w0, w1);
      *(u16x8*)&Bl[(B ^ 1) * 8192 + bd1] = cvt8b(w2, w3);
    }
    asm volatile("s_waitcnt lgkmcnt(0)" ::: "memory");
    __builtin_amdgcn_s_barrier();
  }
#undef DN_ADMA

  // epilogue: scale by route weight, atomic accumulate
#pragma unroll
  for (int mi = 0; mi < 8; ++mi)
#pragma unroll
    for (int ni = 0; ni < 4; ++ni)
#pragma unroll
      for (int r = 0; r < 4; ++r) {
        int grow = wrM * 128 + mi * 16 + lk * 4 + r;
        if (grow < vr) {
          int col = hb + wrN * 64 + ni * 16 + lrow;
          float val = acc[mi][ni][r] * sPw[grow];
          unsafeAtomicAdd(&y[(size_t)sTok[grow] * H_DIM + col], val);
        }
      }
}

extern "C" void kernel_launch(void* const* d_in, const int* in_sizes, int n_in,
                              void* d_out, int out_size, void* d_ws, size_t ws_size,
                              hipStream_t stream) {
  const float* x  = (const float*)d_in[0];
  const float* wr = (const float*)d_in[1];
  const float* wg = (const float*)d_in[2];
  const float* wu = (const float*)d_in[3];
  const float* wd = (const float*)d_in[4];
  float* y = (float*)d_out;

  char* ws = (char*)d_ws;
  int* counts    = (int*)(ws + 0);
  int* offsets   = (int*)(ws + 256);
  int* cursor    = (int*)(ws + 512);
  int* n_tiles   = (int*)(ws + 768);
  int* tile_list = (int*)(ws + 1024);
  int*   topk_id    = (int*)(ws + 2048);
  float* topk_w     = (float*)(ws + 2048 + 1 * 65536);
  int*   pair_token = (int*)(ws + 2048 + 2 * 65536);
  float* pair_w     = (float*)(ws + 2048 + 3 * 65536);
  ushort_t* h_buf = (ushort_t*)(ws + 2048 + 4 * 65536);  // 25.2 MB
  ushort_t* xb = (ushort_t*)(ws + 2048 + 4 * 65536 + (size_t)T_TOK * I_DIM * K_TOP * 2);  // 4 MB

  hipMemsetAsync(counts, 0, 256, stream);
  hipMemsetAsync(y, 0, (size_t)T_TOK * H_DIM * sizeof(float), stream);

  xcast_kernel<<<(T_TOK * H_DIM / 8) / 256, 256, 0, stream>>>(x, xb);
  router_kernel<<<T_TOK / 4, 64, 0, stream>>>(x, wr, topk_id, topk_w, counts);
  scan_kernel<<<1, 64, 0, stream>>>(counts, offsets, cursor, tile_list, n_tiles);
  build_kernel<<<(T_TOK * K_TOP) / 256, 256, 0, stream>>>(topk_id, topk_w, cursor, pair_token, pair_w);
  gemm_gu_kernel<<<128 * 6, 512, 0, stream>>>(
      xb, wg, wu, offsets, counts, pair_token, tile_list, n_tiles, h_buf);
  gemm_down_kernel<<<128 * 4, 512, 0, stream>>>(
      h_buf, wd, offsets, counts, pair_token, pair_w, tile_list, n_tiles, y);
}

// Round 16
// 585.168 us; speedup vs baseline: 1.0026x; 1.0026x over previous
//
#include <hip/hip_runtime.h>
#include <hip/hip_bf16.h>
#include <cstdint>
#include <cstddef>

// Qwen3 MoE layer: T=2048 tokens, H=1024 hidden, E=64 experts, I=768, top-K=8
#define T_TOK 2048
#define H_DIM 1024
#define E_NUM 64
#define I_DIM 768
#define K_TOP 8

typedef __attribute__((ext_vector_type(8))) __bf16 bf16x8;
typedef __attribute__((ext_vector_type(8))) unsigned short u16x8;
typedef __attribute__((ext_vector_type(4))) float f32x4;
typedef unsigned short ushort_t;

__device__ __forceinline__ unsigned short f2bf(float f) {
  uint32_t u = __builtin_bit_cast(uint32_t, f);
  u += 0x7fffu + ((u >> 16) & 1u);
  return (unsigned short)(u >> 16);
}

__device__ __forceinline__ u16x8 cvt8b(f32x4 a, f32x4 b) {
  bf16x8 r;
  r[0] = (__bf16)a[0]; r[1] = (__bf16)a[1]; r[2] = (__bf16)a[2]; r[3] = (__bf16)a[3];
  r[4] = (__bf16)b[0]; r[5] = (__bf16)b[1]; r[6] = (__bf16)b[2]; r[7] = (__bf16)b[3];
  return __builtin_bit_cast(u16x8, r);
}

// async 16B global -> LDS; dest = wave-uniform base (HW adds lane*16)
__device__ __forceinline__ void async16(const void* l, const void* g) {
  __builtin_amdgcn_global_load_lds(
      (const __attribute__((address_space(1))) unsigned int*)g,
      (__attribute__((address_space(3))) unsigned int*)l, 16, 0, 0);
}

// Bijective XCD-contiguous decode over the ACTIVE index space [0, n_act)
__device__ __forceinline__ int xcd_decode(int wg0, int n_act) {
  int q = n_act >> 3, r = n_act & 7;
  int xcd = wg0 & 7, rank = wg0 >> 3;
  int cnt = q + (xcd < r ? 1 : 0);
  if (rank >= cnt) return -1;
  return (xcd < r ? xcd * (q + 1) : r * (q + 1) + (xcd - r) * q) + rank;
}

// ---------------- x f32 -> bf16 pre-cast ----------------
__global__ __launch_bounds__(256) void xcast_kernel(const float* __restrict__ x,
                                                    ushort_t* __restrict__ xb) {
  int i = blockIdx.x * 256 + threadIdx.x;
  const f32x4* s = (const f32x4*)(x + (size_t)i * 8);
  *(u16x8*)(xb + (size_t)i * 8) = cvt8b(s[0], s[1]);
}

// ---------------- router: 4 tokens/block ----------------
__global__ __launch_bounds__(64) void router_kernel(
    const float* __restrict__ x, const float* __restrict__ wr,
    int* __restrict__ topk_id, float* __restrict__ topk_w,
    int* __restrict__ counts) {
  const int t0 = blockIdx.x * 4;
  const int e = threadIdx.x;
  const float4* wv = (const float4*)(wr + (size_t)e * H_DIM);
  const float4* xv0 = (const float4*)(x + (size_t)t0 * H_DIM);
  const float4* xv1 = (const float4*)(x + (size_t)(t0 + 1) * H_DIM);
  const float4* xv2 = (const float4*)(x + (size_t)(t0 + 2) * H_DIM);
  const float4* xv3 = (const float4*)(x + (size_t)(t0 + 3) * H_DIM);
  float acc0 = 0.f, acc1 = 0.f, acc2 = 0.f, acc3 = 0.f;
#pragma unroll 4
  for (int i = 0; i < H_DIM / 4; ++i) {
    float4 b = wv[i];
    float4 a0 = xv0[i], a1 = xv1[i], a2 = xv2[i], a3 = xv3[i];
    acc0 = fmaf(a0.x, b.x, fmaf(a0.y, b.y, fmaf(a0.z, b.z, fmaf(a0.w, b.w, acc0))));
    acc1 = fmaf(a1.x, b.x, fmaf(a1.y, b.y, fmaf(a1.z, b.z, fmaf(a1.w, b.w, acc1))));
    acc2 = fmaf(a2.x, b.x, fmaf(a2.y, b.y, fmaf(a2.z, b.z, fmaf(a2.w, b.w, acc2))));
    acc3 = fmaf(a3.x, b.x, fmaf(a3.y, b.y, fmaf(a3.z, b.z, fmaf(a3.w, b.w, acc3))));
  }
  float accs[4] = {acc0, acc1, acc2, acc3};
#pragma unroll 1
  for (int tt = 0; tt < 4; ++tt) {
    int t = t0 + tt;
    float acc = accs[tt];
    float m = acc;
    for (int o = 32; o; o >>= 1) m = fmaxf(m, __shfl_xor(m, o));
    float p = __expf(acc - m);
    float s = p;
    for (int o = 32; o; o >>= 1) s += __shfl_xor(s, o);
    p /= s;
    float v = p;
    int sid = 0;
    float sw = 0.f;
    for (int k = 0; k < K_TOP; ++k) {
      float bv = v;
      int bi = e;
      for (int o = 32; o; o >>= 1) {
        float ov = __shfl_xor(bv, o);
        int oi = __shfl_xor(bi, o);
        if (ov > bv || (ov == bv && oi < bi)) { bv = ov; bi = oi; }
      }
      if (e == k) { sid = bi; sw = bv; }
      if (e == bi) v = -1.f;
    }
    float ssum = (e < K_TOP) ? sw : 0.f;
    for (int o = 32; o; o >>= 1) ssum += __shfl_xor(ssum, o);
    if (e < K_TOP) {
      topk_id[t * K_TOP + e] = sid;
      topk_w[t * K_TOP + e] = sw / ssum;
      atomicAdd(&counts[sid], 1);
    }
  }
}

// ---------------- scan: offsets + tile list (BM=256, max 2 tiles/expert) ----------------
__global__ __launch_bounds__(64) void scan_kernel(
    const int* __restrict__ counts, int* __restrict__ offsets,
    int* __restrict__ cursor, int* __restrict__ tile_list,
    int* __restrict__ n_tiles) {
  int e = threadIdx.x;
  int ne = counts[e];
  int x = ne;
  for (int o = 1; o < 64; o <<= 1) {
    int v = __shfl_up(x, o);
    if (e >= o) x += v;
  }
  int excl = x - ne;
  offsets[e] = excl;
  cursor[e] = excl;
  int ntl = (ne + 255) >> 8;
  if (ntl > 2) ntl = 2;
  int y2 = ntl;
  for (int o = 1; o < 64; o <<= 1) {
    int v = __shfl_up(y2, o);
    if (e >= o) y2 += v;
  }
  int texcl = y2 - ntl;
  for (int m = 0; m < ntl; ++m) tile_list[texcl + m] = (e << 2) | m;
  if (e == 63) *n_tiles = texcl + ntl;
}

__global__ __launch_bounds__(256) void build_kernel(
    const int* __restrict__ topk_id, const float* __restrict__ topk_w,
    int* __restrict__ cursor, int* __restrict__ pair_token, float* __restrict__ pair_w) {
  int i = blockIdx.x * 256 + threadIdx.x;
  int t = i >> 3;
  int e = topk_id[i];
  int pos = atomicAdd(&cursor[e], 1);
  pair_token[pos] = t;
  pair_w[pos] = topk_w[i];
}

// bf16 LDS rows: 32 bf16 = 4 chunks of 16B; chunk slot = c ^ ((row>>1)&3)

// ================= stage 1: h = silu(X Wg^T) * (X Wu^T) =================
// Block 256(M tokens) x 256(N = 128 G-rows || 128 U-rows of one I-block), BK=32.
// 8 waves 2M x 4N, wave tile 128x64, acc = 128 VGPR.
// launch_bounds(512,1): hipcc arg2 = min BLOCKS/CU (CUDA semantics) -> 1 block/CU
// -> 2 waves/SIMD -> 256-VGPR budget -> no spill (R14/R15 failed at the 128 cap).
#define GU_NIT 32

__global__ __launch_bounds__(512, 1) void gemm_gu_kernel(
    const ushort_t* __restrict__ xb, const float* __restrict__ wg,
    const float* __restrict__ wu, const int* __restrict__ offsets,
    const int* __restrict__ counts, const int* __restrict__ pair_token,
    const int* __restrict__ tile_list, const int* __restrict__ n_tiles,
    ushort_t* __restrict__ h_buf) {
  int idx = xcd_decode(blockIdx.x, (*n_tiles) * 6);
  if (idx < 0) return;
  int tl = idx / 6, nt = idx - tl * 6;
  int ent = tile_list[tl];
  int e = ent >> 2, mt = ent & 3;
  int ne = counts[e], off = offsets[e];
  int ib = nt * 128;
  int vr = ne - mt * 256;
  if (vr <= 0) return;
  if (vr > 256) vr = 256;

  // arena: X 2x16KB @0, B 2x16KB @32K, sTok @64K; epilogue reuses [0,64K) as f32 ex
  __shared__ __align__(16) char L[66560];
  ushort_t* Xs = (ushort_t*)L;
  ushort_t* Bl = (ushort_t*)(L + 32768);
  int* sTok = (int*)(L + 65536);

  const int tid = threadIdx.x;
  const int lane = tid & 63;
  const int wid = tid >> 6;            // 0..7
  const int wrM = wid >> 2, wrN = wid & 3;  // 2M x 4N
  const int lrow = lane & 15, lk = lane >> 4;

  if (tid < 256) {
    int p = mt * 256 + tid;
    sTok[tid] = pair_token[off + (p < ne ? p : ne - 1)];
  }
  __syncthreads();

  // X DMA: 1024 chunks of 16B, 2/thread; linear dest + inverse-swizzled src
  const ushort_t* xsrc[2];
  int xdst[2];
#pragma unroll
  for (int j = 0; j < 2; ++j) {
    int p = j * 512 + tid;
    int row = p >> 2, c = p & 3;
    xsrc[j] = xb + (size_t)sTok[row] * H_DIM + ((c ^ ((row >> 1) & 3)) << 3);
    xdst[j] = (j * 512 + wid * 64) * 8;
  }
  // W staging: row brow = tid>>1 (0-127 G, 128-255 U), chunk pair (tid&1)
  const int brow = tid >> 1;
  const int cs0 = (tid & 1) * 2, cs1 = cs0 + 1;
  const float* bq = (brow < 128)
      ? wg + ((size_t)e * I_DIM + ib + brow) * H_DIM
      : wu + ((size_t)e * I_DIM + ib + brow - 128) * H_DIM;
  const float* bsrc0 = bq + cs0 * 8;
  const float* bsrc1 = bq + cs1 * 8;
  const int bd0 = (brow * 4 + (cs0 ^ ((brow >> 1) & 3))) * 8;
  const int bd1 = (brow * 4 + (cs1 ^ ((brow >> 1) & 3))) * 8;

  const bool wact = (wrM * 128) < vr;

  f32x4 acc[8][4];
#pragma unroll
  for (int mi = 0; mi < 8; ++mi)
#pragma unroll
    for (int ni = 0; ni < 4; ++ni) acc[mi][ni] = f32x4{0.f, 0.f, 0.f, 0.f};

#define GU_XDMA(B, K0)                                 \
  do {                                                 \
    async16(&Xs[(B) * 8192 + xdst[0]], xsrc[0] + (K0)); \
    async16(&Xs[(B) * 8192 + xdst[1]], xsrc[1] + (K0)); \
  } while (0)

  f32x4 w0, w1, w2, w3;
  // prologue: tile 0 into buf 0
  GU_XDMA(0, 0);
  w0 = *(const f32x4*)(bsrc0);
  w1 = *(const f32x4*)(bsrc0 + 4);
  w2 = *(const f32x4*)(bsrc1);
  w3 = *(const f32x4*)(bsrc1 + 4);
  *(u16x8*)&Bl[bd0] = cvt8b(w0, w1);
  *(u16x8*)&Bl[bd1] = cvt8b(w2, w3);
  asm volatile("s_waitcnt vmcnt(0) lgkmcnt(0)" ::: "memory");
  __builtin_amdgcn_s_barrier();

#pragma unroll 1
  for (int K = 0; K < GU_NIT; ++K) {
    const int B = K & 1;
    if (K + 1 < GU_NIT) {
      const int kn = (K + 1) * 32;
      GU_XDMA(B ^ 1, kn);
      w0 = *(const f32x4*)(bsrc0 + kn);
      w1 = *(const f32x4*)(bsrc0 + kn + 4);
      w2 = *(const f32x4*)(bsrc1 + kn);
      w3 = *(const f32x4*)(bsrc1 + kn + 4);
    }
    if (wact) {
      u16x8 bf[4];
#pragma unroll
      for (int ni = 0; ni < 4; ++ni) {
        int br = wrN * 64 + ni * 16 + lrow;
        bf[ni] = *(const u16x8*)&Bl[B * 8192 + br * 32 + ((lk ^ ((br >> 1) & 3)) << 3)];
      }
#pragma unroll
      for (int mi = 0; mi < 8; ++mi) {
        int r = wrM * 128 + mi * 16 + lrow;
        u16x8 af = *(const u16x8*)&Xs[B * 8192 + r * 32 + ((lk ^ ((r >> 1) & 3)) << 3)];
#pragma unroll
        for (int ni = 0; ni < 4; ++ni)
          acc[mi][ni] = __builtin_amdgcn_mfma_f32_16x16x32_bf16(
              __builtin_bit_cast(bf16x8, af), __builtin_bit_cast(bf16x8, bf[ni]),
              acc[mi][ni], 0, 0, 0);
      }
    }
    asm volatile("s_waitcnt vmcnt(0)" ::: "memory");
    if (K + 1 < GU_NIT) {
      *(u16x8*)&Bl[(B ^ 1) * 8192 + bd0] = cvt8b(w0, w1);
      *(u16x8*)&Bl[(B ^ 1) * 8192 + bd1] = cvt8b(w2, w3);
    }
    asm volatile("s_waitcnt lgkmcnt(0)" ::: "memory");
    __builtin_amdgcn_s_barrier();
  }
#undef GU_XDMA

  // epilogue: cross-wave SwiGLU via f32 LDS exchange, 2 rounds (q = 0,1)
  float* ex = (float*)L;  // [256 rows][64 cols] = 64 KB
#pragma unroll 1
  for (int q = 0; q < 2; ++q) {
    if (wrN == 2 + q) {  // U waves dump
#pragma unroll
      for (int mi = 0; mi < 8; ++mi)
#pragma unroll
        for (int ni = 0; ni < 4; ++ni)
#pragma unroll
          for (int r = 0; r < 4; ++r)
            ex[(wrM * 128 + mi * 16 + lk * 4 + r) * 64 + ni * 16 + lrow] = acc[mi][ni][r];
    }
    __syncthreads();
    if (wrN == q) {  // G waves consume + store h
#pragma unroll
      for (int mi = 0; mi < 8; ++mi)
#pragma unroll
        for (int ni = 0; ni < 4; ++ni)
#pragma unroll
          for (int r = 0; r < 4; ++r) {
            int grow = wrM * 128 + mi * 16 + lk * 4 + r;
            if (grow < vr) {
              float g = acc[mi][ni][r];
              float u = ex[grow * 64 + ni * 16 + lrow];
              float hv = g / (1.f + __expf(-g)) * u;
              int col = ib + q * 64 + ni * 16 + lrow;
              h_buf[(size_t)(off + mt * 256 + grow) * I_DIM + col] = f2bf(hv);
            }
          }
    }
    __syncthreads();
  }
}

// ================= stage 2: y += route_w * (h Wd^T) =================
// Block 256(M) x 256(N H-cols), BK=32, 8 waves 2M x 4N, wave 128x64, acc=128.
#define DN_NIT 24

__global__ __launch_bounds__(512, 1) void gemm_down_kernel(
    const ushort_t* __restrict__ h_buf, const float* __restrict__ wd,
    const int* __restrict__ offsets, const int* __restrict__ counts,
    const int* __restrict__ pair_token, const float* __restrict__ pair_w,
    const int* __restrict__ tile_list, const int* __restrict__ n_tiles,
    float* __restrict__ y) {
  int idx = xcd_decode(blockIdx.x, (*n_tiles) * 4);
  if (idx < 0) return;
  int tl = idx >> 2, nt = idx & 3;
  int ent = tile_list[tl];
  int e = ent >> 2, mt = ent & 3;
  int ne = counts[e], off = offsets[e];
  int hb = nt * 256;
  int vr = ne - mt * 256;
  if (vr <= 0) return;
  if (vr > 256) vr = 256;

  __shared__ __align__(16) char L[67584];  // A 2x16K @0, B 2x16K @32K, tok/pw @64K
  ushort_t* Ah = (ushort_t*)L;
  ushort_t* Bl = (ushort_t*)(L + 32768);
  int* sTok = (int*)(L + 65536);
  float* sPw = (float*)(L + 66560);

  const int tid = threadIdx.x;
  const int lane = tid & 63;
  const int wid = tid >> 6;
  const int wrM = wid >> 2, wrN = wid & 3;
  const int lrow = lane & 15, lk = lane >> 4;

  if (tid < 256) {
    int p = mt * 256 + tid;
    int ix = off + (p < ne ? p : ne - 1);
    sTok[tid] = pair_token[ix];
    sPw[tid] = pair_w[ix];
  }
  __syncthreads();

  const ushort_t* asrc[2];
  int adst[2];
#pragma unroll
  for (int j = 0; j < 2; ++j) {
    int p = j * 512 + tid;
    int row = p >> 2, c = p & 3;
    int pr = mt * 256 + row;
    int hr = off + (pr < ne ? pr : ne - 1);
    asrc[j] = h_buf + (size_t)hr * I_DIM + ((c ^ ((row >> 1) & 3)) << 3);
    adst[j] = (j * 512 + wid * 64) * 8;
  }
  // Wd staging: row brow = tid>>1 (H-col hb+brow), chunk pair (tid&1)
  const int brow = tid >> 1;
  const int cs0 = (tid & 1) * 2, cs1 = cs0 + 1;
  const float* bq = wd + ((size_t)e * H_DIM + hb + brow) * I_DIM;
  const float* bsrc0 = bq + cs0 * 8;
  const float* bsrc1 = bq + cs1 * 8;
  const int bd0 = (brow * 4 + (cs0 ^ ((brow >> 1) & 3))) * 8;
  const int bd1 = (brow * 4 + (cs1 ^ ((brow >> 1) & 3))) * 8;

  const bool wact = (wrM * 128) < vr;

  f32x4 acc[8][4];
#pragma unroll
  for (int mi = 0; mi < 8; ++mi)
#pragma unroll
    for (int ni = 0; ni < 4; ++ni) acc[mi][ni] = f32x4{0.f, 0.f, 0.f, 0.f};

#define DN_ADMA(B, K0)                                  \
  do {                                                  \
    async16(&Ah[(B) * 8192 + adst[0]], asrc[0] + (K0)); \
    async16(&Ah[(B) * 8192 + adst[1]], asrc[1] + (K0)); \
  } while (0)

  f32x4 w0, w1, w2, w3;
  DN_ADMA(0, 0);
  w0 = *(const f32x4*)(bsrc0);
  w1 = *(const f32x4*)(bsrc0 + 4);
  w2 = *(const f32x4*)(bsrc1);
  w3 = *(const f32x4*)(bsrc1 + 4);
  *(u16x8*)&Bl[bd0] = cvt8b(w0, w1);
  *(u16x8*)&Bl[bd1] = cvt8b(w2, w3);
  asm volatile("s_waitcnt vmcnt(0) lgkmcnt(0)" ::: "memory");
  __builtin_amdgcn_s_barrier();

#pragma unroll 1
  for (int K = 0; K < DN_NIT; ++K) {
    const int B = K & 1;
    if (K + 1 < DN_NIT) {
      const int kn = (K + 1) * 32;
      DN_ADMA(B ^ 1, kn);
      w0 = *(const f32x4*)(bsrc0 + kn);
      w1 = *(const f32x4*)(bsrc0 + kn + 4);
      w2 = *(const f32x4*)(bsrc1 + kn);
      w3 = *(const f32x4*)(bsrc1 + kn + 4);
    }
    if (wact) {
      u16x8 bf[4];
#pragma unroll
      for (int ni = 0; ni < 4; ++ni) {
        int br = wrN * 64 + ni * 16 + lrow;
        bf[ni] = *(const u16x8*)&Bl[B * 8192 + br * 32 + ((lk ^ ((br >> 1) & 3)) << 3)];
      }
#pragma unroll
      for (int mi = 0; mi < 8; ++mi) {
        int r = wrM * 128 + mi * 16 + lrow;
        u16x8 af = *(const u16x8*)&Ah[B * 8192 + r * 32 + ((lk ^ ((r >> 1) & 3)) << 3)];
#pragma unroll
        for (int ni = 0; ni < 4; ++ni)
          acc[mi][ni] = __builtin_amdgcn_mfma_f32_16x16x32_bf16(
              __builtin_bit_cast(bf16x8, af), __builtin_bit_cast(bf16x8, bf[ni]),
              acc[mi][ni], 0, 0, 0);
      }
    }
    asm volatile("s_waitcnt vmcnt(0)" ::: "memory");
    if (K + 1 < DN_NIT) {
      *(u16x8*)&Bl[(B ^ 1) * 8192 + bd0] = cvt8b(w0, w1);
      *(u16x8*)&Bl[(B ^ 1) * 8192 + bd1] = cvt8b(w2, w3);
    }
    asm volatile("s_waitcnt lgkmcnt(0)" ::: "memory");
    __builtin_amdgcn_s_barrier();
  }
#undef DN_ADMA

  // epilogue: scale by route weight, atomic accumulate
#pragma unroll
  for (int mi = 0; mi < 8; ++mi)
#pragma unroll
    for (int ni = 0; ni < 4; ++ni)
#pragma unroll
      for (int r = 0; r < 4; ++r) {
        int grow = wrM * 128 + mi * 16 + lk * 4 + r;
        if (grow < vr) {
          int col = hb + wrN * 64 + ni * 16 + lrow;
          float val = acc[mi][ni][r] * sPw[grow];
          unsafeAtomicAdd(&y[(size_t)sTok[grow] * H_DIM + col], val);
        }
      }
}

extern "C" void kernel_launch(void* const* d_in, const int* in_sizes, int n_in,
                              void* d_out, int out_size, void* d_ws, size_t ws_size,
                              hipStream_t stream) {
  const float* x  = (const float*)d_in[0];
  const float* wr = (const float*)d_in[1];
  const float* wg = (const float*)d_in[2];
  const float* wu = (const float*)d_in[3];
  const float* wd = (const float*)d_in[4];
  float* y = (float*)d_out;

  char* ws = (char*)d_ws;
  int* counts    = (int*)(ws + 0);
  int* offsets   = (int*)(ws + 256);
  int* cursor    = (int*)(ws + 512);
  int* n_tiles   = (int*)(ws + 768);
  int* tile_list = (int*)(ws + 1024);
  int*   topk_id    = (int*)(ws + 2048);
  float* topk_w     = (float*)(ws + 2048 + 1 * 65536);
  int*   pair_token = (int*)(ws + 2048 + 2 * 65536);
  float* pair_w     = (float*)(ws + 2048 + 3 * 65536);
  ushort_t* h_buf = (ushort_t*)(ws + 2048 + 4 * 65536);  // 25.2 MB
  ushort_t* xb = (ushort_t*)(ws + 2048 + 4 * 65536 + (size_t)T_TOK * I_DIM * K_TOP * 2);  // 4 MB

  hipMemsetAsync(counts, 0, 256, stream);
  hipMemsetAsync(y, 0, (size_t)T_TOK * H_DIM * sizeof(float), stream);

  xcast_kernel<<<(T_TOK * H_DIM / 8) / 256, 256, 0, stream>>>(x, xb);
  router_kernel<<<T_TOK / 4, 64, 0, stream>>>(x, wr, topk_id, topk_w, counts);
  scan_kernel<<<1, 64, 0, stream>>>(counts, offsets, cursor, tile_list, n_tiles);
  build_kernel<<<(T_TOK * K_TOP) / 256, 256, 0, stream>>>(topk_id, topk_w, cursor, pair_token, pair_w);
  gemm_gu_kernel<<<128 * 6, 512, 0, stream>>>(
      xb, wg, wu, offsets, counts, pair_token, tile_list, n_tiles, h_buf);
  gemm_down_kernel<<<128 * 4, 512, 0, stream>>>(
      h_buf, wd, offsets, counts, pair_token, pair_w, tile_list, n_tiles, y);
}

// Round 17
// 372.683 us; speedup vs baseline: 1.5742x; 1.5701x over previous
//
#include <hip/hip_runtime.h>
#include <hip/hip_bf16.h>
#include <cstdint>
#include <cstddef>

// Qwen3 MoE layer: T=2048 tokens, H=1024 hidden, E=64 experts, I=768, top-K=8
// Final configuration (best measured: 372.6 us total).
// gemm_gu:   BM=384 (whole expert), BN=64(G+U), BK=32, 12 waves, 2 blocks/CU,
//            T3-minimal 1-barrier loop, X via global_load_lds, W reg-staged.
// gemm_down: BM=384, BN=128, BK=32, same schedule.
// Static bijective XCD decode keeps each expert's panels on one XCD's L2.
#define T_TOK 2048
#define H_DIM 1024
#define E_NUM 64
#define I_DIM 768
#define K_TOP 8
#define BM 384  // one tile covers any expert: ne ~ Binom(16384,1/64) = 256 +/- 16

typedef __attribute__((ext_vector_type(8))) __bf16 bf16x8;
typedef __attribute__((ext_vector_type(4))) __bf16 bf16x4;
typedef __attribute__((ext_vector_type(8))) unsigned short u16x8;
typedef __attribute__((ext_vector_type(4))) float f32x4;
typedef unsigned short ushort_t;

__device__ __forceinline__ unsigned short f2bf(float f) {
  uint32_t u = __builtin_bit_cast(uint32_t, f);
  u += 0x7fffu + ((u >> 16) & 1u);
  return (unsigned short)(u >> 16);
}

__device__ __forceinline__ bf16x8 cvt8b(f32x4 a, f32x4 b) {
  bf16x8 r;
  r[0] = (__bf16)a[0]; r[1] = (__bf16)a[1]; r[2] = (__bf16)a[2]; r[3] = (__bf16)a[3];
  r[4] = (__bf16)b[0]; r[5] = (__bf16)b[1]; r[6] = (__bf16)b[2]; r[7] = (__bf16)b[3];
  return r;
}

__device__ __forceinline__ bf16x4 cvt4b(f32x4 a) {
  bf16x4 r;
  r[0] = (__bf16)a[0]; r[1] = (__bf16)a[1]; r[2] = (__bf16)a[2]; r[3] = (__bf16)a[3];
  return r;
}

// async 16B global -> LDS; dest = wave-uniform base (HW adds lane*16)
__device__ __forceinline__ void async16(const void* l, const void* g) {
  __builtin_amdgcn_global_load_lds(
      (const __attribute__((address_space(1))) unsigned int*)g,
      (__attribute__((address_space(3))) unsigned int*)l, 16, 0, 0);
}

// ---------------- x f32 -> bf16 pre-cast ----------------
__global__ __launch_bounds__(256) void xcast_kernel(const float* __restrict__ x,
                                                    ushort_t* __restrict__ xb) {
  int i = blockIdx.x * 256 + threadIdx.x;
  const f32x4* s = (const f32x4*)(x + (size_t)i * 8);
  *(bf16x8*)(xb + (size_t)i * 8) = cvt8b(s[0], s[1]);
}

// ---------------- router: 4 tokens/block; wr chunk kept in regs across tokens ----------------
__global__ __launch_bounds__(64) void router_kernel(
    const float* __restrict__ x, const float* __restrict__ wr,
    int* __restrict__ topk_id, float* __restrict__ topk_w,
    int* __restrict__ counts) {
  const int t0 = blockIdx.x * 4;
  const int e = threadIdx.x;
  const float4* wv = (const float4*)(wr + (size_t)e * H_DIM);
  const float4* xv0 = (const float4*)(x + (size_t)t0 * H_DIM);
  const float4* xv1 = (const float4*)(x + (size_t)(t0 + 1) * H_DIM);
  const float4* xv2 = (const float4*)(x + (size_t)(t0 + 2) * H_DIM);
  const float4* xv3 = (const float4*)(x + (size_t)(t0 + 3) * H_DIM);
  float acc0 = 0.f, acc1 = 0.f, acc2 = 0.f, acc3 = 0.f;
#pragma unroll 4
  for (int i = 0; i < H_DIM / 4; ++i) {
    float4 b = wv[i];
    float4 a0 = xv0[i], a1 = xv1[i], a2 = xv2[i], a3 = xv3[i];
    acc0 = fmaf(a0.x, b.x, fmaf(a0.y, b.y, fmaf(a0.z, b.z, fmaf(a0.w, b.w, acc0))));
    acc1 = fmaf(a1.x, b.x, fmaf(a1.y, b.y, fmaf(a1.z, b.z, fmaf(a1.w, b.w, acc1))));
    acc2 = fmaf(a2.x, b.x, fmaf(a2.y, b.y, fmaf(a2.z, b.z, fmaf(a2.w, b.w, acc2))));
    acc3 = fmaf(a3.x, b.x, fmaf(a3.y, b.y, fmaf(a3.z, b.z, fmaf(a3.w, b.w, acc3))));
  }
  float accs[4] = {acc0, acc1, acc2, acc3};
#pragma unroll 1
  for (int tt = 0; tt < 4; ++tt) {
    int t = t0 + tt;
    float acc = accs[tt];
    float m = acc;
    for (int o = 32; o; o >>= 1) m = fmaxf(m, __shfl_xor(m, o));
    float p = __expf(acc - m);
    float s = p;
    for (int o = 32; o; o >>= 1) s += __shfl_xor(s, o);
    p /= s;
    float v = p;
    int sid = 0;
    float sw = 0.f;
    for (int k = 0; k < K_TOP; ++k) {
      float bv = v;
      int bi = e;
      for (int o = 32; o; o >>= 1) {
        float ov = __shfl_xor(bv, o);
        int oi = __shfl_xor(bi, o);
        if (ov > bv || (ov == bv && oi < bi)) { bv = ov; bi = oi; }
      }
      if (e == k) { sid = bi; sw = bv; }
      if (e == bi) v = -1.f;
    }
    float ssum = (e < K_TOP) ? sw : 0.f;
    for (int o = 32; o; o >>= 1) ssum += __shfl_xor(ssum, o);
    if (e < K_TOP) {
      topk_id[t * K_TOP + e] = sid;
      topk_w[t * K_TOP + e] = sw / ssum;
      atomicAdd(&counts[sid], 1);
    }
  }
}

// ---------------- wave-parallel scan ----------------
__global__ __launch_bounds__(64) void scan_kernel(
    const int* __restrict__ counts, int* __restrict__ offsets,
    int* __restrict__ cursor) {
  int e = threadIdx.x;
  int ne = counts[e];
  int x = ne;
  for (int o = 1; o < 64; o <<= 1) {
    int v = __shfl_up(x, o);
    if (e >= o) x += v;
  }
  int excl = x - ne;
  offsets[e] = excl;
  cursor[e] = excl;
}

__global__ __launch_bounds__(256) void build_kernel(
    const int* __restrict__ topk_id, const float* __restrict__ topk_w,
    int* __restrict__ cursor, int* __restrict__ pair_token, float* __restrict__ pair_w) {
  int i = blockIdx.x * 256 + threadIdx.x;
  int t = i >> 3;
  int e = topk_id[i];
  int pos = atomicAdd(&cursor[e], 1);
  pair_token[pos] = t;
  pair_w[pos] = topk_w[i];
}

// bf16 LDS rows of 32 bf16 (64 B = 4 chunks of 16 B); chunk slot = c ^ ((row>>1)&3)

// ================= stage 1: h = silu(X Wg^T) * (X Wu^T) =================
#define GU_NIT 32

__global__ __launch_bounds__(768, 3) void gemm_gu_kernel(
    const ushort_t* __restrict__ xb, const float* __restrict__ wg,
    const float* __restrict__ wu, const int* __restrict__ offsets,
    const int* __restrict__ counts, const int* __restrict__ pair_token,
    ushort_t* __restrict__ h_buf) {
  int idx = (blockIdx.x & 7) * 96 + (blockIdx.x >> 3);  // static bijective XCD decode
  int e = idx / 12, nt = idx - e * 12;
  int ne = counts[e], off = offsets[e];
  int ib = nt * 64;

  __shared__ __align__(16) ushort_t Xs[2][BM * 32];   // 24 KB x2
  __shared__ __align__(16) ushort_t Gs[2][64 * 32];   //  4 KB x2
  __shared__ __align__(16) ushort_t Us[2][64 * 32];   //  4 KB x2
  __shared__ int sTok[BM];

  const int tid = threadIdx.x;
  const int lane = tid & 63;
  const int wid = tid >> 6;  // 0..11
  if (tid < BM) {
    sTok[tid] = pair_token[off + (tid < ne ? tid : ne - 1)];
  }
  __syncthreads();

  const ushort_t* xsrc[2];
#pragma unroll
  for (int j = 0; j < 2; ++j) {
    int p = j * 768 + tid;
    int row = p >> 2, c = p & 3;
    xsrc[j] = xb + (size_t)sTok[row] * H_DIM + ((c ^ ((row >> 1) & 3)) << 3);
  }
  const float* gsrc = wg;
  const float* usrc = wu;
  int wdsti = 0;
  if (wid < 8) {
    int wrow = tid >> 3, wq = tid & 7;
    size_t ro = ((size_t)e * I_DIM + ib + wrow) * H_DIM + wq * 4;
    gsrc = wg + ro;
    usrc = wu + ro;
    wdsti = wrow * 32 + (((wq >> 1) ^ ((wrow >> 1) & 3)) << 3) + ((wq & 1) << 2);
  }

  const int wrM = wid >> 1, wrN = wid & 1;
  const int lrow = lane & 15, lk = lane >> 4;
  const bool wact = (wrM * 64) < ne;

  f32x4 accG[4][2], accU[4][2];
#pragma unroll
  for (int mi = 0; mi < 4; ++mi)
#pragma unroll
    for (int ni = 0; ni < 2; ++ni) {
      accG[mi][ni] = f32x4{0.f, 0.f, 0.f, 0.f};
      accU[mi][ni] = f32x4{0.f, 0.f, 0.f, 0.f};
    }

  f32x4 gA = {0, 0, 0, 0}, uA = {0, 0, 0, 0};

#define GU_XDMA(B, K0)                                             \
  do {                                                             \
    async16(&Xs[B][(wid * 64) * 8], xsrc[0] + (K0));               \
    async16(&Xs[B][(768 + wid * 64) * 8], xsrc[1] + (K0));         \
  } while (0)

  GU_XDMA(0, 0);
  if (wid < 8) {
    gA = *(const f32x4*)(gsrc);
    uA = *(const f32x4*)(usrc);
  }
  asm volatile("s_waitcnt vmcnt(0)" ::: "memory");
  __builtin_amdgcn_sched_barrier(0);
  if (wid < 8) {
    *(bf16x4*)&Gs[0][wdsti] = cvt4b(gA);
    *(bf16x4*)&Us[0][wdsti] = cvt4b(uA);
  }
  asm volatile("s_waitcnt lgkmcnt(0)" ::: "memory");
  __builtin_amdgcn_s_barrier();
  __builtin_amdgcn_sched_barrier(0);

#pragma unroll 2
  for (int K = 0; K < GU_NIT; ++K) {
    const int B = K & 1;
    if (K + 1 < GU_NIT) {
      GU_XDMA(B ^ 1, (K + 1) * 32);
      if (wid < 8) {
        gA = *(const f32x4*)(gsrc + (K + 1) * 32);
        uA = *(const f32x4*)(usrc + (K + 1) * 32);
      }
    }
    if (wact) {
      __builtin_amdgcn_s_setprio(1);
      bf16x8 af[4];
#pragma unroll
      for (int mi = 0; mi < 4; ++mi) {
        int r = wrM * 64 + mi * 16 + lrow;
        af[mi] = __builtin_bit_cast(
            bf16x8, *(const u16x8*)&Xs[B][r * 32 + ((lk ^ ((r >> 1) & 3)) << 3)]);
      }
#pragma unroll
      for (int ni = 0; ni < 2; ++ni) {
        int br = wrN * 32 + ni * 16 + lrow;
        int ci = br * 32 + ((lk ^ ((br >> 1) & 3)) << 3);
        bf16x8 bg = __builtin_bit_cast(bf16x8, *(const u16x8*)&Gs[B][ci]);
        bf16x8 bu = __builtin_bit_cast(bf16x8, *(const u16x8*)&Us[B][ci]);
#pragma unroll
        for (int mi = 0; mi < 4; ++mi) {
          accG[mi][ni] = __builtin_amdgcn_mfma_f32_16x16x32_bf16(af[mi], bg, accG[mi][ni], 0, 0, 0);
          accU[mi][ni] = __builtin_amdgcn_mfma_f32_16x16x32_bf16(af[mi], bu, accU[mi][ni], 0, 0, 0);
        }
      }
      __builtin_amdgcn_s_setprio(0);
    }
    asm volatile("s_waitcnt vmcnt(0)" ::: "memory");
    __builtin_amdgcn_sched_barrier(0);
    if (K + 1 < GU_NIT && wid < 8) {
      *(bf16x4*)&Gs[B ^ 1][wdsti] = cvt4b(gA);
      *(bf16x4*)&Us[B ^ 1][wdsti] = cvt4b(uA);
    }
    asm volatile("s_waitcnt lgkmcnt(0)" ::: "memory");
    __builtin_amdgcn_s_barrier();
    __builtin_amdgcn_sched_barrier(0);
  }
#undef GU_XDMA

#pragma unroll
  for (int mi = 0; mi < 4; ++mi)
#pragma unroll
    for (int ni = 0; ni < 2; ++ni)
#pragma unroll
      for (int r = 0; r < 4; ++r) {
        int grow = wrM * 64 + mi * 16 + lk * 4 + r;
        if (grow < ne) {
          int col = ib + wrN * 32 + ni * 16 + lrow;
          float g = accG[mi][ni][r], u = accU[mi][ni][r];
          float hv = g / (1.f + __expf(-g)) * u;
          h_buf[(size_t)(off + grow) * I_DIM + col] = f2bf(hv);
        }
      }
}

// ================= stage 2: y += route_w * (h Wd^T) =================
#define DN_NIT 24

__global__ __launch_bounds__(768, 3) void gemm_down_kernel(
    const ushort_t* __restrict__ h_buf, const float* __restrict__ wd,
    const int* __restrict__ offsets, const int* __restrict__ counts,
    const int* __restrict__ pair_token, const float* __restrict__ pair_w,
    float* __restrict__ y) {
  int idx = (blockIdx.x & 7) * 64 + (blockIdx.x >> 3);
  int e = idx >> 3, nt = idx & 7;
  int ne = counts[e], off = offsets[e];
  int hb = nt * 128;

  __shared__ __align__(16) ushort_t Ah[2][BM * 32];   // 24 KB x2
  __shared__ __align__(16) ushort_t Bs[2][128 * 32];  //  8 KB x2
  __shared__ int sTok[BM];
  __shared__ float sPw[BM];

  const int tid = threadIdx.x;
  const int lane = tid & 63;
  const int wid = tid >> 6;
  if (tid < BM) {
    int ix = off + (tid < ne ? tid : ne - 1);
    sTok[tid] = pair_token[ix];
    sPw[tid] = pair_w[ix];
  }
  __syncthreads();

  const ushort_t* asrc[2];
#pragma unroll
  for (int j = 0; j < 2; ++j) {
    int p = j * 768 + tid;
    int row = p >> 2, c = p & 3;
    int hr = off + (row < ne ? row : ne - 1);
    asrc[j] = h_buf + (size_t)hr * I_DIM + ((c ^ ((row >> 1) & 3)) << 3);
  }
  const float* bsrc0 = wd;
  const float* bsrc1 = wd;
  int bdst0 = 0, bdst1 = 0;
  if (wid < 8) {
    int r0 = tid >> 3, q0 = tid & 7;
    bsrc0 = wd + ((size_t)e * H_DIM + hb + r0) * I_DIM + q0 * 4;
    bdst0 = r0 * 32 + (((q0 >> 1) ^ ((r0 >> 1) & 3)) << 3) + ((q0 & 1) << 2);
    int p1 = 512 + tid;
    int r1 = p1 >> 3, q1 = p1 & 7;
    bsrc1 = wd + ((size_t)e * H_DIM + hb + r1) * I_DIM + q1 * 4;
    bdst1 = r1 * 32 + (((q1 >> 1) ^ ((r1 >> 1) & 3)) << 3) + ((q1 & 1) << 2);
  }

  const int wrM = wid >> 1, wrN = wid & 1;
  const int lrow = lane & 15, lk = lane >> 4;
  const bool wact = (wrM * 64) < ne;

  f32x4 acc[4][4];
#pragma unroll
  for (int mi = 0; mi < 4; ++mi)
#pragma unroll
    for (int ni = 0; ni < 4; ++ni) acc[mi][ni] = f32x4{0.f, 0.f, 0.f, 0.f};

  f32x4 bA = {0, 0, 0, 0}, bB = {0, 0, 0, 0};

#define DN_ADMA(B, K0)                                             \
  do {                                                             \
    async16(&Ah[B][(wid * 64) * 8], asrc[0] + (K0));               \
    async16(&Ah[B][(768 + wid * 64) * 8], asrc[1] + (K0));         \
  } while (0)

  DN_ADMA(0, 0);
  if (wid < 8) {
    bA = *(const f32x4*)(bsrc0);
    bB = *(const f32x4*)(bsrc1);
  }
  asm volatile("s_waitcnt vmcnt(0)" ::: "memory");
  __builtin_amdgcn_sched_barrier(0);
  if (wid < 8) {
    *(bf16x4*)&Bs[0][bdst0] = cvt4b(bA);
    *(bf16x4*)&Bs[0][bdst1] = cvt4b(bB);
  }
  asm volatile("s_waitcnt lgkmcnt(0)" ::: "memory");
  __builtin_amdgcn_s_barrier();
  __builtin_amdgcn_sched_barrier(0);

#pragma unroll 2
  for (int K = 0; K < DN_NIT; ++K) {
    const int B = K & 1;
    if (K + 1 < DN_NIT) {
      DN_ADMA(B ^ 1, (K + 1) * 32);
      if (wid < 8) {
        bA = *(const f32x4*)(bsrc0 + (K + 1) * 32);
        bB = *(const f32x4*)(bsrc1 + (K + 1) * 32);
      }
    }
    if (wact) {
      __builtin_amdgcn_s_setprio(1);
      bf16x8 af[4];
#pragma unroll
      for (int mi = 0; mi < 4; ++mi) {
        int r = wrM * 64 + mi * 16 + lrow;
        af[mi] = __builtin_bit_cast(
            bf16x8, *(const u16x8*)&Ah[B][r * 32 + ((lk ^ ((r >> 1) & 3)) << 3)]);
      }
#pragma unroll
      for (int ni = 0; ni < 4; ++ni) {
        int br = wrN * 64 + ni * 16 + lrow;
        bf16x8 bb = __builtin_bit_cast(
            bf16x8, *(const u16x8*)&Bs[B][br * 32 + ((lk ^ ((br >> 1) & 3)) << 3)]);
#pragma unroll
        for (int mi = 0; mi < 4; ++mi)
          acc[mi][ni] = __builtin_amdgcn_mfma_f32_16x16x32_bf16(af[mi], bb, acc[mi][ni], 0, 0, 0);
      }
      __builtin_amdgcn_s_setprio(0);
    }
    asm volatile("s_waitcnt vmcnt(0)" ::: "memory");
    __builtin_amdgcn_sched_barrier(0);
    if (K + 1 < DN_NIT && wid < 8) {
      *(bf16x4*)&Bs[B ^ 1][bdst0] = cvt4b(bA);
      *(bf16x4*)&Bs[B ^ 1][bdst1] = cvt4b(bB);
    }
    asm volatile("s_waitcnt lgkmcnt(0)" ::: "memory");
    __builtin_amdgcn_s_barrier();
    __builtin_amdgcn_sched_barrier(0);
  }
#undef DN_ADMA

#pragma unroll
  for (int mi = 0; mi < 4; ++mi)
#pragma unroll
    for (int ni = 0; ni < 4; ++ni)
#pragma unroll
      for (int r = 0; r < 4; ++r) {
        int grow = wrM * 64 + mi * 16 + lk * 4 + r;
        if (grow < ne) {
          int col = hb + wrN * 64 + ni * 16 + lrow;
          float val = acc[mi][ni][r] * sPw[grow];
          unsafeAtomicAdd(&y[(size_t)sTok[grow] * H_DIM + col], val);
        }
      }
}

extern "C" void kernel_launch(void* const* d_in, const int* in_sizes, int n_in,
                              void* d_out, int out_size, void* d_ws, size_t ws_size,
                              hipStream_t stream) {
  const float* x  = (const float*)d_in[0];
  const float* wr = (const float*)d_in[1];
  const float* wg = (const float*)d_in[2];
  const float* wu = (const float*)d_in[3];
  const float* wd = (const float*)d_in[4];
  float* y = (float*)d_out;

  char* ws = (char*)d_ws;
  int* counts    = (int*)(ws + 0);
  int* offsets   = (int*)(ws + 256);
  int* cursor    = (int*)(ws + 512);
  int*   topk_id    = (int*)(ws + 2048);
  float* topk_w     = (float*)(ws + 2048 + 1 * 65536);
  int*   pair_token = (int*)(ws + 2048 + 2 * 65536);
  float* pair_w     = (float*)(ws + 2048 + 3 * 65536);
  ushort_t* h_buf = (ushort_t*)(ws + 2048 + 4 * 65536);  // 25.2 MB
  ushort_t* xb = (ushort_t*)(ws + 2048 + 4 * 65536 + (size_t)T_TOK * I_DIM * K_TOP * 2);  // 4 MB

  hipMemsetAsync(counts, 0, 256, stream);
  hipMemsetAsync(y, 0, (size_t)T_TOK * H_DIM * sizeof(float), stream);

  xcast_kernel<<<(T_TOK * H_DIM / 8) / 256, 256, 0, stream>>>(x, xb);
  router_kernel<<<T_TOK / 4, 64, 0, stream>>>(x, wr, topk_id, topk_w, counts);
  scan_kernel<<<1, 64, 0, stream>>>(counts, offsets, cursor);
  build_kernel<<<(T_TOK * K_TOP) / 256, 256, 0, stream>>>(topk_id, topk_w, cursor, pair_token, pair_w);
  gemm_gu_kernel<<<768, 768, 0, stream>>>(
      xb, wg, wu, offsets, counts, pair_token, h_buf);
  gemm_down_kernel<<<512, 768, 0, stream>>>(
      h_buf, wd, offsets, counts, pair_token, pair_w, y);
}